// Round 2
// baseline (11777.211 us; speedup 1.0000x reference)
//
#include <hip/hip_runtime.h>

#define N_NODES 100000
#define N_EDGES 3200000
#define IN_DIM 512
#define OUT_DIM 256

#define MB 32      // rows per GEMM block
#define KT 32      // k tile
#define WPAD 36    // padded row stride (words) for W tile: 36*4=144B, 16B-aligned, odd multiple of 4 words -> 8 bank-starts

// ---------------------------------------------------------------------------
// Fused GEMM (fp32 vector) + bias + ReLU + row L2 normalize.
// Block: 256 threads (4 waves), computes 32 rows x 256 cols.
// Wave w owns rows r0=8w..8w+7 entirely -> norm is a pure wave shfl reduce.
// Thread: 8 rows x 4 cols (cols lane, lane+64, lane+128, lane+192).
// ---------------------------------------------------------------------------
__global__ __launch_bounds__(256, 3) void gemm_relu_norm(
    const float* __restrict__ h, const float* __restrict__ W,
    const float* __restrict__ b, float* __restrict__ z)
{
    __shared__ float hs[MB][KT];          // 4 KB
    __shared__ float ws[OUT_DIM][WPAD];   // 36 KB

    const int tid  = threadIdx.x;
    const int lane = tid & 63;
    const int wave = tid >> 6;
    const int r0   = wave * 8;
    const int m0   = blockIdx.x * MB;     // 100000 % 32 == 0, no tail

    float acc[8][4];
#pragma unroll
    for (int i = 0; i < 8; i++)
#pragma unroll
        for (int j = 0; j < 4; j++) acc[i][j] = 0.f;

    // staging maps (coalesced 128B segments per 8 lanes)
    const int srow = tid >> 3;            // 0..31
    const int skj  = (tid & 7) * 4;       // 0,4,...,28

    for (int kt = 0; kt < IN_DIM; kt += KT) {
        // global loads first (registers), then sync, then LDS writes
        float4 hv = *(const float4*)&h[(size_t)(m0 + srow) * IN_DIM + kt + skj];
        float4 wv[8];
#pragma unroll
        for (int i = 0; i < 8; i++) {
            int c = srow + 32 * i;        // covers 0..255
            wv[i] = *(const float4*)&W[(size_t)c * IN_DIM + kt + skj];
        }
        __syncthreads();                  // previous tile fully consumed
        *(float4*)&hs[srow][skj] = hv;
#pragma unroll
        for (int i = 0; i < 8; i++) {
            int c = srow + 32 * i;
            *(float4*)&ws[c][skj] = wv[i];
        }
        __syncthreads();

#pragma unroll
        for (int kc = 0; kc < KT / 4; kc++) {
            float4 wr[4];
#pragma unroll
            for (int j = 0; j < 4; j++)
                wr[j] = *(const float4*)&ws[lane + 64 * j][kc * 4];
            float4 hr[8];
#pragma unroll
            for (int i = 0; i < 8; i++)   // broadcast reads (wave-uniform addr)
                hr[i] = *(const float4*)&hs[r0 + i][kc * 4];
#pragma unroll
            for (int i = 0; i < 8; i++)
#pragma unroll
                for (int j = 0; j < 4; j++) {
                    acc[i][j] += hr[i].x * wr[j].x;
                    acc[i][j] += hr[i].y * wr[j].y;
                    acc[i][j] += hr[i].z * wr[j].z;
                    acc[i][j] += hr[i].w * wr[j].w;
                }
        }
    }

    // epilogue: bias + relu + L2 norm per row + store
#pragma unroll
    for (int i = 0; i < 8; i++) {
        float v[4];
        float sumsq = 0.f;
#pragma unroll
        for (int j = 0; j < 4; j++) {
            float t = acc[i][j] + b[lane + 64 * j];
            t = t > 0.f ? t : 0.f;
            v[j] = t;
            sumsq += t * t;
        }
#pragma unroll
        for (int off = 32; off; off >>= 1) sumsq += __shfl_xor(sumsq, off, 64);
        float scale = 1.f / fmaxf(sqrtf(sumsq), 1e-12f);
        size_t row = (size_t)(m0 + r0 + i) * OUT_DIM;
#pragma unroll
        for (int j = 0; j < 4; j++)
            z[row + lane + 64 * j] = v[j] * scale;
    }
}

// ---------------------------------------------------------------------------
// Edge aggregation: one wave per edge. Lane l moves z[src][4l..4l+3] into
// sums[dst][...] via scalar f32 atomics. Lane 0 also counts the degree.
// ---------------------------------------------------------------------------
__global__ __launch_bounds__(256) void agg_kernel(
    const float* __restrict__ z, const int* __restrict__ src,
    const int* __restrict__ dst, float* __restrict__ sums,
    unsigned int* __restrict__ deg)
{
    int e = blockIdx.x * 4 + (threadIdx.x >> 6);
    if (e >= N_EDGES) return;
    int lane = threadIdx.x & 63;
    int s = src[e];
    int d = dst[e];
    if (lane == 0) atomicAdd(&deg[d], 1u);
    float4 v = *(const float4*)&z[(size_t)s * OUT_DIM + lane * 4];
    float* o = &sums[(size_t)d * OUT_DIM + lane * 4];
    atomicAdd(o + 0, v.x);
    atomicAdd(o + 1, v.y);
    atomicAdd(o + 2, v.z);
    atomicAdd(o + 3, v.w);
}

// ---------------------------------------------------------------------------
// mean = deg>0 ? sums/deg : 0  (in place)
// ---------------------------------------------------------------------------
__global__ __launch_bounds__(256) void finalize_kernel(
    float* __restrict__ sums, const unsigned int* __restrict__ deg)
{
    size_t i = (size_t)blockIdx.x * blockDim.x + threadIdx.x;
    if (i < (size_t)N_NODES * OUT_DIM) {
        unsigned int dg = deg[i >> 8];   // OUT_DIM == 256
        float s = sums[i];
        sums[i] = dg > 0 ? s / (float)dg : 0.f;
    }
}

extern "C" void kernel_launch(void* const* d_in, const int* in_sizes, int n_in,
                              void* d_out, int out_size, void* d_ws, size_t ws_size,
                              hipStream_t stream)
{
    const float* h   = (const float*)d_in[0];
    const float* W   = (const float*)d_in[1];
    const float* b   = (const float*)d_in[2];
    const int*   src = (const int*)d_in[3];
    const int*   dst = (const int*)d_in[4];

    float* z    = (float*)d_out;                         // [N_NODES, OUT_DIM]
    float* mean = z + (size_t)N_NODES * OUT_DIM;         // [N_NODES, OUT_DIM]
    unsigned int* deg = (unsigned int*)d_ws;             // N_NODES u32

    hipMemsetAsync(mean, 0, (size_t)N_NODES * OUT_DIM * sizeof(float), stream);
    hipMemsetAsync(deg, 0, (size_t)N_NODES * sizeof(unsigned int), stream);

    gemm_relu_norm<<<N_NODES / MB, 256, 0, stream>>>(h, W, b, z);
    agg_kernel<<<N_EDGES / 4, 256, 0, stream>>>(z, src, dst, mean, deg);
    finalize_kernel<<<((size_t)N_NODES * OUT_DIM + 255) / 256, 256, 0, stream>>>(mean, deg);
}

// Round 4
// 1888.414 us; speedup vs baseline: 6.2366x; 6.2366x over previous
//
#include <hip/hip_runtime.h>

#define N_NODES 100000
#define N_EDGES 3200000
#define IN_DIM 512
#define OUT_DIM 256

#define MB 32      // rows per GEMM block
#define KT 32      // k tile
#define WPAD 36    // padded row stride (words) for W tile

// ---------------------------------------------------------------------------
// Fused GEMM (fp32 vector) + bias + ReLU + row L2 normalize.  (unchanged)
// Block: 256 threads (4 waves), computes 32 rows x 256 cols.
// ---------------------------------------------------------------------------
__global__ __launch_bounds__(256, 3) void gemm_relu_norm(
    const float* __restrict__ h, const float* __restrict__ W,
    const float* __restrict__ b, float* __restrict__ z)
{
    __shared__ float hs[MB][KT];          // 4 KB
    __shared__ float ws[OUT_DIM][WPAD];   // 36 KB

    const int tid  = threadIdx.x;
    const int lane = tid & 63;
    const int wave = tid >> 6;
    const int r0   = wave * 8;
    const int m0   = blockIdx.x * MB;

    float acc[8][4];
#pragma unroll
    for (int i = 0; i < 8; i++)
#pragma unroll
        for (int j = 0; j < 4; j++) acc[i][j] = 0.f;

    const int srow = tid >> 3;
    const int skj  = (tid & 7) * 4;

    for (int kt = 0; kt < IN_DIM; kt += KT) {
        float4 hv = *(const float4*)&h[(size_t)(m0 + srow) * IN_DIM + kt + skj];
        float4 wv[8];
#pragma unroll
        for (int i = 0; i < 8; i++) {
            int c = srow + 32 * i;
            wv[i] = *(const float4*)&W[(size_t)c * IN_DIM + kt + skj];
        }
        __syncthreads();
        *(float4*)&hs[srow][skj] = hv;
#pragma unroll
        for (int i = 0; i < 8; i++) {
            int c = srow + 32 * i;
            *(float4*)&ws[c][skj] = wv[i];
        }
        __syncthreads();

#pragma unroll
        for (int kc = 0; kc < KT / 4; kc++) {
            float4 wr[4];
#pragma unroll
            for (int j = 0; j < 4; j++)
                wr[j] = *(const float4*)&ws[lane + 64 * j][kc * 4];
            float4 hr[8];
#pragma unroll
            for (int i = 0; i < 8; i++)
                hr[i] = *(const float4*)&hs[r0 + i][kc * 4];
#pragma unroll
            for (int i = 0; i < 8; i++)
#pragma unroll
                for (int j = 0; j < 4; j++) {
                    acc[i][j] += hr[i].x * wr[j].x;
                    acc[i][j] += hr[i].y * wr[j].y;
                    acc[i][j] += hr[i].z * wr[j].z;
                    acc[i][j] += hr[i].w * wr[j].w;
                }
        }
    }

#pragma unroll
    for (int i = 0; i < 8; i++) {
        float v[4];
        float sumsq = 0.f;
#pragma unroll
        for (int j = 0; j < 4; j++) {
            float t = acc[i][j] + b[lane + 64 * j];
            t = t > 0.f ? t : 0.f;
            v[j] = t;
            sumsq += t * t;
        }
#pragma unroll
        for (int off = 32; off; off >>= 1) sumsq += __shfl_xor(sumsq, off, 64);
        float scale = 1.f / fmaxf(sqrtf(sumsq), 1e-12f);
        size_t row = (size_t)(m0 + r0 + i) * OUT_DIM;
#pragma unroll
        for (int j = 0; j < 4; j++)
            z[row + lane + 64 * j] = v[j] * scale;
    }
}

// ---------------------------------------------------------------------------
// CSR build: degree histogram
// ---------------------------------------------------------------------------
__global__ __launch_bounds__(256) void hist_kernel(
    const int* __restrict__ dst, unsigned* __restrict__ deg)
{
    int e = blockIdx.x * 256 + threadIdx.x;
    if (e < N_EDGES) atomicAdd(&deg[dst[e]], 1u);
}

// ---------------------------------------------------------------------------
// Single-block exclusive scan of deg[0..N_NODES) -> offs (shfl-based)
// ---------------------------------------------------------------------------
__global__ __launch_bounds__(1024) void scan_kernel(
    const unsigned* __restrict__ deg, unsigned* __restrict__ offs)
{
    __shared__ unsigned wtot[16];
    __shared__ unsigned blktot;
    const int tid = threadIdx.x, lane = tid & 63, w = tid >> 6;
    unsigned carry = 0;
    for (int base = 0; base < N_NODES; base += 1024) {
        int i = base + tid;
        unsigned v = (i < N_NODES) ? deg[i] : 0u;
        unsigned incl = v;
#pragma unroll
        for (int off = 1; off < 64; off <<= 1) {
            unsigned t = __shfl_up(incl, off, 64);
            if (lane >= off) incl += t;
        }
        if (lane == 63) wtot[w] = incl;
        __syncthreads();
        if (w == 0) {
            unsigned x = (lane < 16) ? wtot[lane] : 0u;
            unsigned inc2 = x;
#pragma unroll
            for (int off = 1; off < 16; off <<= 1) {
                unsigned t = __shfl_up(inc2, off, 64);
                if (lane >= off) inc2 += t;
            }
            if (lane < 16) wtot[lane] = inc2 - x;   // exclusive wave offset
            if (lane == 15) blktot = inc2;
        }
        __syncthreads();
        if (i < N_NODES) offs[i] = carry + wtot[w] + incl - v;
        carry += blktot;
        __syncthreads();   // protect wtot/blktot before next iteration writes
    }
}

// ---------------------------------------------------------------------------
// Scatter src ids into dst-sorted order
// ---------------------------------------------------------------------------
__global__ __launch_bounds__(256) void scatter_kernel(
    const int* __restrict__ src, const int* __restrict__ dst,
    unsigned* __restrict__ cursor, int* __restrict__ ssrc)
{
    int e = blockIdx.x * 256 + threadIdx.x;
    if (e < N_EDGES) {
        unsigned p = atomicAdd(&cursor[dst[e]], 1u);
        ssrc[p] = src[e];
    }
}

// ---------------------------------------------------------------------------
// One wave per node: gather z rows of its in-edges, register-accumulate, mean.
// ---------------------------------------------------------------------------
__global__ __launch_bounds__(256) void gather_mean(
    const float* __restrict__ z, const int* __restrict__ ssrc,
    const unsigned* __restrict__ offs, const unsigned* __restrict__ deg,
    float* __restrict__ mean)
{
    int n = blockIdx.x * 4 + (threadIdx.x >> 6);
    if (n >= N_NODES) return;
    const int lane = threadIdx.x & 63;
    const unsigned start = offs[n];
    const unsigned dg = deg[n];

    float4 acc = {0.f, 0.f, 0.f, 0.f};
    for (unsigned base = 0; base < dg; base += 64) {
        int cnt = (int)min(64u, dg - base);
        int s_l = (lane < cnt) ? ssrc[start + base + lane] : 0;
        int j = 0;
        for (; j + 4 <= cnt; j += 4) {
            int s0 = __shfl(s_l, j, 64);
            int s1 = __shfl(s_l, j + 1, 64);
            int s2 = __shfl(s_l, j + 2, 64);
            int s3 = __shfl(s_l, j + 3, 64);
            float4 v0 = *(const float4*)&z[(size_t)s0 * OUT_DIM + lane * 4];
            float4 v1 = *(const float4*)&z[(size_t)s1 * OUT_DIM + lane * 4];
            float4 v2 = *(const float4*)&z[(size_t)s2 * OUT_DIM + lane * 4];
            float4 v3 = *(const float4*)&z[(size_t)s3 * OUT_DIM + lane * 4];
            acc.x += v0.x + v1.x + v2.x + v3.x;
            acc.y += v0.y + v1.y + v2.y + v3.y;
            acc.z += v0.z + v1.z + v2.z + v3.z;
            acc.w += v0.w + v1.w + v2.w + v3.w;
        }
        for (; j < cnt; j++) {
            int s = __shfl(s_l, j, 64);
            float4 v = *(const float4*)&z[(size_t)s * OUT_DIM + lane * 4];
            acc.x += v.x; acc.y += v.y; acc.z += v.z; acc.w += v.w;
        }
    }
    float scale = dg > 0 ? 1.f / (float)dg : 0.f;
    float4 o = {acc.x * scale, acc.y * scale, acc.z * scale, acc.w * scale};
    *(float4*)&mean[(size_t)n * OUT_DIM + lane * 4] = o;
}

// ---------------------------------------------------------------------------
// Fallback path (small ws): original atomic aggregation
// ---------------------------------------------------------------------------
__global__ __launch_bounds__(256) void agg_kernel(
    const float* __restrict__ z, const int* __restrict__ src,
    const int* __restrict__ dst, float* __restrict__ sums,
    unsigned int* __restrict__ deg)
{
    int e = blockIdx.x * 4 + (threadIdx.x >> 6);
    if (e >= N_EDGES) return;
    int lane = threadIdx.x & 63;
    int s = src[e];
    int d = dst[e];
    if (lane == 0) atomicAdd(&deg[d], 1u);
    float4 v = *(const float4*)&z[(size_t)s * OUT_DIM + lane * 4];
    float* o = &sums[(size_t)d * OUT_DIM + lane * 4];
    atomicAdd(o + 0, v.x);
    atomicAdd(o + 1, v.y);
    atomicAdd(o + 2, v.z);
    atomicAdd(o + 3, v.w);
}

__global__ __launch_bounds__(256) void finalize_kernel(
    float* __restrict__ sums, const unsigned int* __restrict__ deg)
{
    size_t i = (size_t)blockIdx.x * blockDim.x + threadIdx.x;
    if (i < (size_t)N_NODES * OUT_DIM) {
        unsigned int dg = deg[i >> 8];
        float s = sums[i];
        sums[i] = dg > 0 ? s / (float)dg : 0.f;
    }
}

extern "C" void kernel_launch(void* const* d_in, const int* in_sizes, int n_in,
                              void* d_out, int out_size, void* d_ws, size_t ws_size,
                              hipStream_t stream)
{
    const float* h   = (const float*)d_in[0];
    const float* W   = (const float*)d_in[1];
    const float* b   = (const float*)d_in[2];
    const int*   src = (const int*)d_in[3];
    const int*   dst = (const int*)d_in[4];

    float* z    = (float*)d_out;                         // [N_NODES, OUT_DIM]
    float* mean = z + (size_t)N_NODES * OUT_DIM;         // [N_NODES, OUT_DIM]

    // workspace layout (u32 words): deg | offs | cursor | ssrc
    const size_t PAD = 100352;                           // >= N_NODES, 16B-mult
    unsigned* deg    = (unsigned*)d_ws;
    unsigned* offs   = deg + PAD;
    unsigned* cursor = offs + PAD;
    int*      ssrc   = (int*)(cursor + PAD);
    const size_t need = (PAD * 3 + (size_t)N_EDGES) * sizeof(unsigned);

    gemm_relu_norm<<<N_NODES / MB, 256, 0, stream>>>(h, W, b, z);

    if (ws_size >= need) {
        hipMemsetAsync(deg, 0, N_NODES * sizeof(unsigned), stream);
        hist_kernel<<<(N_EDGES + 255) / 256, 256, 0, stream>>>(dst, deg);
        scan_kernel<<<1, 1024, 0, stream>>>(deg, offs);
        hipMemcpyAsync(cursor, offs, N_NODES * sizeof(unsigned),
                       hipMemcpyDeviceToDevice, stream);
        scatter_kernel<<<(N_EDGES + 255) / 256, 256, 0, stream>>>(src, dst, cursor, ssrc);
        gather_mean<<<(N_NODES + 3) / 4, 256, 0, stream>>>(z, ssrc, offs, deg, mean);
    } else {
        hipMemsetAsync(mean, 0, (size_t)N_NODES * OUT_DIM * sizeof(float), stream);
        hipMemsetAsync(deg, 0, N_NODES * sizeof(unsigned), stream);
        agg_kernel<<<N_EDGES / 4, 256, 0, stream>>>(z, src, dst, mean, deg);
        finalize_kernel<<<((size_t)N_NODES * OUT_DIM + 255) / 256, 256, 0, stream>>>(mean, deg);
    }
}

// Round 6
// 1341.749 us; speedup vs baseline: 8.7775x; 1.4074x over previous
//
#include <hip/hip_runtime.h>

#define N_NODES 100000
#define N_EDGES 3200000
#define IN_DIM 512
#define OUT_DIM 256

typedef unsigned short ushort_t;
typedef __bf16 bf16x8 __attribute__((ext_vector_type(8)));
typedef float f32x16 __attribute__((ext_vector_type(16)));

// ===========================================================================
// W split: fp32 -> bf16 hi (truncate) + bf16 lo (RNE of remainder)
// ===========================================================================
__global__ __launch_bounds__(256) void split_w(
    const float* __restrict__ W, ushort_t* __restrict__ Whi, ushort_t* __restrict__ Wlo)
{
    int i = blockIdx.x * 256 + threadIdx.x;          // grid covers 256*512 exactly
    float x = W[i];
    unsigned xb = __float_as_uint(x);
    ushort_t h16 = (ushort_t)(xb >> 16);
    float hf = __uint_as_float((unsigned)h16 << 16);
    __bf16 lb = (__bf16)(x - hf);
    Whi[i] = h16;
    Wlo[i] = __builtin_bit_cast(ushort_t, lb);
}

// ===========================================================================
// MFMA GEMM: z = L2norm(relu(h @ W^T + b)), split-bf16 (3-term) fp32 emulation.
// Block: 256 thr (4 waves), tile 128 rows x 256 cols, K-step 32.
// Wave w owns rows w*32..w*32+31 (all 256 cols) -> norm is wave-local.
// LDS rows: 128 B = [hi 64B | lo 64B], XOR-swizzled (col ^ ((row&7)<<4)).
// ===========================================================================
#define BM 128
#define BK 32

__device__ __forceinline__ int swz(int row, int col) {
    return row * 128 + (col ^ ((row & 7) << 4));
}

__global__ __launch_bounds__(256, 2) void gemm_mfma(
    const float* __restrict__ h, const ushort_t* __restrict__ Whi,
    const ushort_t* __restrict__ Wlo, const float* __restrict__ b,
    float* __restrict__ z)
{
    __shared__ uint4 AsU[BM * 8];        // 16 KB
    __shared__ uint4 BsU[OUT_DIM * 8];   // 32 KB
    unsigned char* As = (unsigned char*)AsU;
    unsigned char* Bs = (unsigned char*)BsU;

    const int tid  = threadIdx.x;
    const int lane = tid & 63;
    const int w    = tid >> 6;
    const int m0   = blockIdx.x * BM;

    f32x16 acc[8];
#pragma unroll
    for (int i = 0; i < 8; i++)
#pragma unroll
        for (int e = 0; e < 16; e++) acc[i][e] = 0.f;

    // bias per n-tile at this lane's column
    float bb[8];
#pragma unroll
    for (int nt = 0; nt < 8; nt++) bb[nt] = b[nt * 32 + (lane & 31)];

    // staging map: thread t stages A row t>>1, k-half (t&1)*16; B row t.
    const int arow = tid >> 1;
    const int akh  = (tid & 1) * 16;     // local k offset (elements)

    for (int k0 = 0; k0 < IN_DIM; k0 += BK) {
        // ---- global loads (before barrier, hide latency) ----
        int grow = m0 + arow; if (grow > N_NODES - 1) grow = N_NODES - 1;
        const float* hp = &h[(size_t)grow * IN_DIM + k0 + akh];
        float4 v0 = *(const float4*)(hp);
        float4 v1 = *(const float4*)(hp + 4);
        float4 v2 = *(const float4*)(hp + 8);
        float4 v3 = *(const float4*)(hp + 12);
        const ushort_t* wh = &Whi[(size_t)tid * IN_DIM + k0];
        const ushort_t* wl = &Wlo[(size_t)tid * IN_DIM + k0];
        uint4 bh0 = *(const uint4*)(wh);
        uint4 bh1 = *(const uint4*)(wh + 8);
        uint4 bh2 = *(const uint4*)(wh + 16);
        uint4 bh3 = *(const uint4*)(wh + 24);
        uint4 bl0 = *(const uint4*)(wl);
        uint4 bl1 = *(const uint4*)(wl + 8);
        uint4 bl2 = *(const uint4*)(wl + 16);
        uint4 bl3 = *(const uint4*)(wl + 24);

        // ---- split h tile to bf16 hi/lo ----
        float f[16];
        f[0]=v0.x; f[1]=v0.y; f[2]=v0.z; f[3]=v0.w;
        f[4]=v1.x; f[5]=v1.y; f[6]=v1.z; f[7]=v1.w;
        f[8]=v2.x; f[9]=v2.y; f[10]=v2.z; f[11]=v2.w;
        f[12]=v3.x; f[13]=v3.y; f[14]=v3.z; f[15]=v3.w;
        unsigned hu[16], lu[16];
#pragma unroll
        for (int e = 0; e < 16; e++) {
            unsigned xb = __float_as_uint(f[e]);
            unsigned h16 = xb >> 16;
            float hf = __uint_as_float(h16 << 16);
            __bf16 lb = (__bf16)(f[e] - hf);
            hu[e] = h16;
            lu[e] = (unsigned)__builtin_bit_cast(ushort_t, lb);
        }
#define PK(a, i) ((a)[i] | ((a)[(i)+1] << 16))
        uint4 hc0 = { PK(hu,0), PK(hu,2), PK(hu,4),  PK(hu,6)  };
        uint4 hc1 = { PK(hu,8), PK(hu,10), PK(hu,12), PK(hu,14) };
        uint4 lc0 = { PK(lu,0), PK(lu,2), PK(lu,4),  PK(lu,6)  };
        uint4 lc1 = { PK(lu,8), PK(lu,10), PK(lu,12), PK(lu,14) };
#undef PK

        __syncthreads();   // previous tile fully consumed

        // A row: [hi 64B | lo 64B]; this thread covers bytes 2*akh..2*akh+31
        *(uint4*)&As[swz(arow, 2 * akh)]       = hc0;
        *(uint4*)&As[swz(arow, 2 * akh + 16)]  = hc1;
        *(uint4*)&As[swz(arow, 64 + 2 * akh)]      = lc0;
        *(uint4*)&As[swz(arow, 64 + 2 * akh + 16)] = lc1;
        // B row tid: hi chunks 0..3, lo chunks 4..7
        *(uint4*)&Bs[swz(tid, 0)]  = bh0;
        *(uint4*)&Bs[swz(tid, 16)] = bh1;
        *(uint4*)&Bs[swz(tid, 32)] = bh2;
        *(uint4*)&Bs[swz(tid, 48)] = bh3;
        *(uint4*)&Bs[swz(tid, 64)]  = bl0;
        *(uint4*)&Bs[swz(tid, 80)]  = bl1;
        *(uint4*)&Bs[swz(tid, 96)]  = bl2;
        *(uint4*)&Bs[swz(tid, 112)] = bl3;

        __syncthreads();

        // ---- compute: 2 sub-steps of K=16 ----
        const int mrow = w * 32 + (lane & 31);
        const int kb   = 16 * (lane >> 5);     // byte offset of this lane's k-group
#pragma unroll
        for (int s = 0; s < 2; s++) {
            bf16x8 Ah = __builtin_bit_cast(bf16x8, *(const uint4*)&As[swz(mrow, s * 32 + kb)]);
            bf16x8 Al = __builtin_bit_cast(bf16x8, *(const uint4*)&As[swz(mrow, 64 + s * 32 + kb)]);
#pragma unroll
            for (int nt = 0; nt < 8; nt++) {
                const int nrow = nt * 32 + (lane & 31);
                bf16x8 Bh = __builtin_bit_cast(bf16x8, *(const uint4*)&Bs[swz(nrow, s * 32 + kb)]);
                bf16x8 Bl = __builtin_bit_cast(bf16x8, *(const uint4*)&Bs[swz(nrow, 64 + s * 32 + kb)]);
                acc[nt] = __builtin_amdgcn_mfma_f32_32x32x16_bf16(Ah, Bh, acc[nt], 0, 0, 0);
                acc[nt] = __builtin_amdgcn_mfma_f32_32x32x16_bf16(Al, Bh, acc[nt], 0, 0, 0);
                acc[nt] = __builtin_amdgcn_mfma_f32_32x32x16_bf16(Ah, Bl, acc[nt], 0, 0, 0);
            }
        }
    }

    // ---- epilogue: bias + relu + wave-local L2 norm + store ----
    // D layout (m74/m101): col = lane&31, row = (reg&3) + 8*(reg>>2) + 4*(lane>>5)
#pragma unroll
    for (int r = 0; r < 16; r++) {
        int mloc = (r & 3) + 8 * (r >> 2) + 4 * (lane >> 5);
        int grow = m0 + w * 32 + mloc;
        float v[8];
        float sumsq = 0.f;
#pragma unroll
        for (int nt = 0; nt < 8; nt++) {
            float t = acc[nt][r] + bb[nt];
            t = t > 0.f ? t : 0.f;
            v[nt] = t;
            sumsq += t * t;
        }
        // reduce across the 32 lanes sharing this row (same lane>>5 half)
#pragma unroll
        for (int off = 16; off; off >>= 1) sumsq += __shfl_xor(sumsq, off, 64);
        float scale = 1.f / fmaxf(sqrtf(sumsq), 1e-12f);
        if (grow < N_NODES) {
            size_t rowb = (size_t)grow * OUT_DIM + (lane & 31);
#pragma unroll
            for (int nt = 0; nt < 8; nt++)
                z[rowb + nt * 32] = v[nt] * scale;
        }
    }
}

// ===========================================================================
// Fallback fp32 vector GEMM (used only if workspace too small)
// ===========================================================================
#define MBF 32
#define KTF 32
#define WPADF 36
__global__ __launch_bounds__(256, 3) void gemm_relu_norm(
    const float* __restrict__ h, const float* __restrict__ W,
    const float* __restrict__ b, float* __restrict__ z)
{
    __shared__ float hs[MBF][KTF];
    __shared__ float ws[OUT_DIM][WPADF];
    const int tid  = threadIdx.x;
    const int lane = tid & 63;
    const int wave = tid >> 6;
    const int r0   = wave * 8;
    const int m0   = blockIdx.x * MBF;
    float acc[8][4];
#pragma unroll
    for (int i = 0; i < 8; i++)
#pragma unroll
        for (int j = 0; j < 4; j++) acc[i][j] = 0.f;
    const int srow = tid >> 3;
    const int skj  = (tid & 7) * 4;
    for (int kt = 0; kt < IN_DIM; kt += KTF) {
        float4 hv = *(const float4*)&h[(size_t)(m0 + srow) * IN_DIM + kt + skj];
        float4 wv[8];
#pragma unroll
        for (int i = 0; i < 8; i++)
            wv[i] = *(const float4*)&W[(size_t)(srow + 32 * i) * IN_DIM + kt + skj];
        __syncthreads();
        *(float4*)&hs[srow][skj] = hv;
#pragma unroll
        for (int i = 0; i < 8; i++)
            *(float4*)&ws[srow + 32 * i][skj] = wv[i];
        __syncthreads();
#pragma unroll
        for (int kc = 0; kc < KTF / 4; kc++) {
            float4 wr[4];
#pragma unroll
            for (int j = 0; j < 4; j++)
                wr[j] = *(const float4*)&ws[lane + 64 * j][kc * 4];
            float4 hr[8];
#pragma unroll
            for (int i = 0; i < 8; i++)
                hr[i] = *(const float4*)&hs[r0 + i][kc * 4];
#pragma unroll
            for (int i = 0; i < 8; i++)
#pragma unroll
                for (int j = 0; j < 4; j++) {
                    acc[i][j] += hr[i].x * wr[j].x;
                    acc[i][j] += hr[i].y * wr[j].y;
                    acc[i][j] += hr[i].z * wr[j].z;
                    acc[i][j] += hr[i].w * wr[j].w;
                }
        }
    }
#pragma unroll
    for (int i = 0; i < 8; i++) {
        float v[4];
        float sumsq = 0.f;
#pragma unroll
        for (int j = 0; j < 4; j++) {
            float t = acc[i][j] + b[lane + 64 * j];
            t = t > 0.f ? t : 0.f;
            v[j] = t;
            sumsq += t * t;
        }
#pragma unroll
        for (int off = 32; off; off >>= 1) sumsq += __shfl_xor(sumsq, off, 64);
        float scale = 1.f / fmaxf(sqrtf(sumsq), 1e-12f);
        size_t row = (size_t)(m0 + r0 + i) * OUT_DIM;
#pragma unroll
        for (int j = 0; j < 4; j++)
            z[row + lane + 64 * j] = v[j] * scale;
    }
}

// ===========================================================================
// CSR build + gather-mean aggregation (unchanged from round 2)
// ===========================================================================
__global__ __launch_bounds__(256) void hist_kernel(
    const int* __restrict__ dst, unsigned* __restrict__ deg)
{
    int e = blockIdx.x * 256 + threadIdx.x;
    if (e < N_EDGES) atomicAdd(&deg[dst[e]], 1u);
}

__global__ __launch_bounds__(1024) void scan_kernel(
    const unsigned* __restrict__ deg, unsigned* __restrict__ offs)
{
    __shared__ unsigned wtot[16];
    __shared__ unsigned blktot;
    const int tid = threadIdx.x, lane = tid & 63, w = tid >> 6;
    unsigned carry = 0;
    for (int base = 0; base < N_NODES; base += 1024) {
        int i = base + tid;
        unsigned v = (i < N_NODES) ? deg[i] : 0u;
        unsigned incl = v;
#pragma unroll
        for (int off = 1; off < 64; off <<= 1) {
            unsigned t = __shfl_up(incl, off, 64);
            if (lane >= off) incl += t;
        }
        if (lane == 63) wtot[w] = incl;
        __syncthreads();
        if (w == 0) {
            unsigned x = (lane < 16) ? wtot[lane] : 0u;
            unsigned inc2 = x;
#pragma unroll
            for (int off = 1; off < 16; off <<= 1) {
                unsigned t = __shfl_up(inc2, off, 64);
                if (lane >= off) inc2 += t;
            }
            if (lane < 16) wtot[lane] = inc2 - x;
            if (lane == 15) blktot = inc2;
        }
        __syncthreads();
        if (i < N_NODES) offs[i] = carry + wtot[w] + incl - v;
        carry += blktot;
        __syncthreads();
    }
}

__global__ __launch_bounds__(256) void scatter_kernel(
    const int* __restrict__ src, const int* __restrict__ dst,
    unsigned* __restrict__ cursor, int* __restrict__ ssrc)
{
    int e = blockIdx.x * 256 + threadIdx.x;
    if (e < N_EDGES) {
        unsigned p = atomicAdd(&cursor[dst[e]], 1u);
        ssrc[p] = src[e];
    }
}

__global__ __launch_bounds__(256) void gather_mean(
    const float* __restrict__ z, const int* __restrict__ ssrc,
    const unsigned* __restrict__ offs, const unsigned* __restrict__ deg,
    float* __restrict__ mean)
{
    int n = blockIdx.x * 4 + (threadIdx.x >> 6);
    if (n >= N_NODES) return;
    const int lane = threadIdx.x & 63;
    const unsigned start = offs[n];
    const unsigned dg = deg[n];

    float4 acc = {0.f, 0.f, 0.f, 0.f};
    for (unsigned base = 0; base < dg; base += 64) {
        int cnt = (int)min(64u, dg - base);
        int s_l = (lane < cnt) ? ssrc[start + base + lane] : 0;
        int j = 0;
        for (; j + 4 <= cnt; j += 4) {
            int s0 = __shfl(s_l, j, 64);
            int s1 = __shfl(s_l, j + 1, 64);
            int s2 = __shfl(s_l, j + 2, 64);
            int s3 = __shfl(s_l, j + 3, 64);
            float4 v0 = *(const float4*)&z[(size_t)s0 * OUT_DIM + lane * 4];
            float4 v1 = *(const float4*)&z[(size_t)s1 * OUT_DIM + lane * 4];
            float4 v2 = *(const float4*)&z[(size_t)s2 * OUT_DIM + lane * 4];
            float4 v3 = *(const float4*)&z[(size_t)s3 * OUT_DIM + lane * 4];
            acc.x += v0.x + v1.x + v2.x + v3.x;
            acc.y += v0.y + v1.y + v2.y + v3.y;
            acc.z += v0.z + v1.z + v2.z + v3.z;
            acc.w += v0.w + v1.w + v2.w + v3.w;
        }
        for (; j < cnt; j++) {
            int s = __shfl(s_l, j, 64);
            float4 v = *(const float4*)&z[(size_t)s * OUT_DIM + lane * 4];
            acc.x += v.x; acc.y += v.y; acc.z += v.z; acc.w += v.w;
        }
    }
    float scale = dg > 0 ? 1.f / (float)dg : 0.f;
    float4 o = {acc.x * scale, acc.y * scale, acc.z * scale, acc.w * scale};
    *(float4*)&mean[(size_t)n * OUT_DIM + lane * 4] = o;
}

__global__ __launch_bounds__(256) void agg_kernel(
    const float* __restrict__ z, const int* __restrict__ src,
    const int* __restrict__ dst, float* __restrict__ sums,
    unsigned int* __restrict__ deg)
{
    int e = blockIdx.x * 4 + (threadIdx.x >> 6);
    if (e >= N_EDGES) return;
    int lane = threadIdx.x & 63;
    int s = src[e];
    int d = dst[e];
    if (lane == 0) atomicAdd(&deg[d], 1u);
    float4 v = *(const float4*)&z[(size_t)s * OUT_DIM + lane * 4];
    float* o = &sums[(size_t)d * OUT_DIM + lane * 4];
    atomicAdd(o + 0, v.x);
    atomicAdd(o + 1, v.y);
    atomicAdd(o + 2, v.z);
    atomicAdd(o + 3, v.w);
}

__global__ __launch_bounds__(256) void finalize_kernel(
    float* __restrict__ sums, const unsigned int* __restrict__ deg)
{
    size_t i = (size_t)blockIdx.x * blockDim.x + threadIdx.x;
    if (i < (size_t)N_NODES * OUT_DIM) {
        unsigned int dg = deg[i >> 8];
        float s = sums[i];
        sums[i] = dg > 0 ? s / (float)dg : 0.f;
    }
}

extern "C" void kernel_launch(void* const* d_in, const int* in_sizes, int n_in,
                              void* d_out, int out_size, void* d_ws, size_t ws_size,
                              hipStream_t stream)
{
    const float* h   = (const float*)d_in[0];
    const float* W   = (const float*)d_in[1];
    const float* b   = (const float*)d_in[2];
    const int*   src = (const int*)d_in[3];
    const int*   dst = (const int*)d_in[4];

    float* z    = (float*)d_out;
    float* mean = z + (size_t)N_NODES * OUT_DIM;

    // ws layout (u32 words): Whi | Wlo | deg | offs | cursor | ssrc
    const size_t WSPLIT = (size_t)OUT_DIM * IN_DIM / 2;   // 65536 u32 per array
    const size_t PAD = 100352;
    unsigned* whi_u  = (unsigned*)d_ws;
    unsigned* wlo_u  = whi_u + WSPLIT;
    unsigned* deg    = wlo_u + WSPLIT;
    unsigned* offs   = deg + PAD;
    unsigned* cursor = offs + PAD;
    int*      ssrc   = (int*)(cursor + PAD);
    const size_t need = (WSPLIT * 2 + PAD * 3 + (size_t)N_EDGES) * sizeof(unsigned);

    if (ws_size >= need) {
        split_w<<<(OUT_DIM * IN_DIM) / 256, 256, 0, stream>>>(
            W, (ushort_t*)whi_u, (ushort_t*)wlo_u);
        gemm_mfma<<<(N_NODES + BM - 1) / BM, 256, 0, stream>>>(
            h, (const ushort_t*)whi_u, (const ushort_t*)wlo_u, b, z);
        hipMemsetAsync(deg, 0, N_NODES * sizeof(unsigned), stream);
        hist_kernel<<<(N_EDGES + 255) / 256, 256, 0, stream>>>(dst, deg);
        scan_kernel<<<1, 1024, 0, stream>>>(deg, offs);
        hipMemcpyAsync(cursor, offs, N_NODES * sizeof(unsigned),
                       hipMemcpyDeviceToDevice, stream);
        scatter_kernel<<<(N_EDGES + 255) / 256, 256, 0, stream>>>(src, dst, cursor, ssrc);
        gather_mean<<<(N_NODES + 3) / 4, 256, 0, stream>>>(z, ssrc, offs, deg, mean);
    } else {
        unsigned* deg2 = (unsigned*)d_ws;
        gemm_relu_norm<<<N_NODES / MBF, 256, 0, stream>>>(h, W, b, z);
        hipMemsetAsync(mean, 0, (size_t)N_NODES * OUT_DIM * sizeof(float), stream);
        hipMemsetAsync(deg2, 0, N_NODES * sizeof(unsigned), stream);
        agg_kernel<<<N_EDGES / 4, 256, 0, stream>>>(z, src, dst, mean, deg2);
        finalize_kernel<<<((size_t)N_NODES * OUT_DIM + 255) / 256, 256, 0, stream>>>(mean, deg2);
    }
}

// Round 8
// 1058.131 us; speedup vs baseline: 11.1302x; 1.2680x over previous
//
#include <hip/hip_runtime.h>

#define N_NODES 100000
#define N_EDGES 3200000
#define IN_DIM 512
#define OUT_DIM 256

typedef unsigned short ushort_t;
typedef __bf16 bf16x8 __attribute__((ext_vector_type(8)));
typedef float f32x16 __attribute__((ext_vector_type(16)));

__device__ __forceinline__ float bf2f(ushort_t u) {
    return __uint_as_float((unsigned)u << 16);
}

// ===========================================================================
// W split: fp32 -> bf16 hi (truncate) + bf16 lo (RNE of remainder)
// ===========================================================================
__global__ __launch_bounds__(256) void split_w(
    const float* __restrict__ W, ushort_t* __restrict__ Whi, ushort_t* __restrict__ Wlo)
{
    int i = blockIdx.x * 256 + threadIdx.x;
    float x = W[i];
    unsigned xb = __float_as_uint(x);
    ushort_t h16 = (ushort_t)(xb >> 16);
    float hf = __uint_as_float((unsigned)h16 << 16);
    __bf16 lb = (__bf16)(x - hf);
    Whi[i] = h16;
    Wlo[i] = __builtin_bit_cast(ushort_t, lb);
}

// ===========================================================================
// MFMA GEMM: z = L2norm(relu(h @ W^T + b)), split-bf16 (3-term).
// Also writes zb = bf16(z) for the aggregation gather (if zb != nullptr).
// ===========================================================================
#define BM 128
#define BK 32

__device__ __forceinline__ int swz(int row, int col) {
    return row * 128 + (col ^ ((row & 7) << 4));
}

__global__ __launch_bounds__(256, 2) void gemm_mfma(
    const float* __restrict__ h, const ushort_t* __restrict__ Whi,
    const ushort_t* __restrict__ Wlo, const float* __restrict__ b,
    float* __restrict__ z, ushort_t* __restrict__ zb)
{
    __shared__ uint4 AsU[BM * 8];        // 16 KB
    __shared__ uint4 BsU[OUT_DIM * 8];   // 32 KB
    unsigned char* As = (unsigned char*)AsU;
    unsigned char* Bs = (unsigned char*)BsU;

    const int tid  = threadIdx.x;
    const int lane = tid & 63;
    const int w    = tid >> 6;
    const int m0   = blockIdx.x * BM;

    f32x16 acc[8];
#pragma unroll
    for (int i = 0; i < 8; i++)
#pragma unroll
        for (int e = 0; e < 16; e++) acc[i][e] = 0.f;

    float bb[8];
#pragma unroll
    for (int nt = 0; nt < 8; nt++) bb[nt] = b[nt * 32 + (lane & 31)];

    const int arow = tid >> 1;
    const int akh  = (tid & 1) * 16;

    for (int k0 = 0; k0 < IN_DIM; k0 += BK) {
        int grow = m0 + arow; if (grow > N_NODES - 1) grow = N_NODES - 1;
        const float* hp = &h[(size_t)grow * IN_DIM + k0 + akh];
        float4 v0 = *(const float4*)(hp);
        float4 v1 = *(const float4*)(hp + 4);
        float4 v2 = *(const float4*)(hp + 8);
        float4 v3 = *(const float4*)(hp + 12);
        const ushort_t* wh = &Whi[(size_t)tid * IN_DIM + k0];
        const ushort_t* wl = &Wlo[(size_t)tid * IN_DIM + k0];
        uint4 bh0 = *(const uint4*)(wh);
        uint4 bh1 = *(const uint4*)(wh + 8);
        uint4 bh2 = *(const uint4*)(wh + 16);
        uint4 bh3 = *(const uint4*)(wh + 24);
        uint4 bl0 = *(const uint4*)(wl);
        uint4 bl1 = *(const uint4*)(wl + 8);
        uint4 bl2 = *(const uint4*)(wl + 16);
        uint4 bl3 = *(const uint4*)(wl + 24);

        float f[16];
        f[0]=v0.x; f[1]=v0.y; f[2]=v0.z; f[3]=v0.w;
        f[4]=v1.x; f[5]=v1.y; f[6]=v1.z; f[7]=v1.w;
        f[8]=v2.x; f[9]=v2.y; f[10]=v2.z; f[11]=v2.w;
        f[12]=v3.x; f[13]=v3.y; f[14]=v3.z; f[15]=v3.w;
        unsigned hu[16], lu[16];
#pragma unroll
        for (int e = 0; e < 16; e++) {
            unsigned xb = __float_as_uint(f[e]);
            unsigned h16 = xb >> 16;
            float hf = __uint_as_float(h16 << 16);
            __bf16 lb = (__bf16)(f[e] - hf);
            hu[e] = h16;
            lu[e] = (unsigned)__builtin_bit_cast(ushort_t, lb);
        }
#define PK(a, i) ((a)[i] | ((a)[(i)+1] << 16))
        uint4 hc0 = { PK(hu,0), PK(hu,2), PK(hu,4),  PK(hu,6)  };
        uint4 hc1 = { PK(hu,8), PK(hu,10), PK(hu,12), PK(hu,14) };
        uint4 lc0 = { PK(lu,0), PK(lu,2), PK(lu,4),  PK(lu,6)  };
        uint4 lc1 = { PK(lu,8), PK(lu,10), PK(lu,12), PK(lu,14) };
#undef PK

        __syncthreads();

        *(uint4*)&As[swz(arow, 2 * akh)]       = hc0;
        *(uint4*)&As[swz(arow, 2 * akh + 16)]  = hc1;
        *(uint4*)&As[swz(arow, 64 + 2 * akh)]      = lc0;
        *(uint4*)&As[swz(arow, 64 + 2 * akh + 16)] = lc1;
        *(uint4*)&Bs[swz(tid, 0)]  = bh0;
        *(uint4*)&Bs[swz(tid, 16)] = bh1;
        *(uint4*)&Bs[swz(tid, 32)] = bh2;
        *(uint4*)&Bs[swz(tid, 48)] = bh3;
        *(uint4*)&Bs[swz(tid, 64)]  = bl0;
        *(uint4*)&Bs[swz(tid, 80)]  = bl1;
        *(uint4*)&Bs[swz(tid, 96)]  = bl2;
        *(uint4*)&Bs[swz(tid, 112)] = bl3;

        __syncthreads();

        const int mrow = w * 32 + (lane & 31);
        const int kb   = 16 * (lane >> 5);
#pragma unroll
        for (int s = 0; s < 2; s++) {
            bf16x8 Ah = __builtin_bit_cast(bf16x8, *(const uint4*)&As[swz(mrow, s * 32 + kb)]);
            bf16x8 Al = __builtin_bit_cast(bf16x8, *(const uint4*)&As[swz(mrow, 64 + s * 32 + kb)]);
#pragma unroll
            for (int nt = 0; nt < 8; nt++) {
                const int nrow = nt * 32 + (lane & 31);
                bf16x8 Bh = __builtin_bit_cast(bf16x8, *(const uint4*)&Bs[swz(nrow, s * 32 + kb)]);
                bf16x8 Bl = __builtin_bit_cast(bf16x8, *(const uint4*)&Bs[swz(nrow, 64 + s * 32 + kb)]);
                acc[nt] = __builtin_amdgcn_mfma_f32_32x32x16_bf16(Ah, Bh, acc[nt], 0, 0, 0);
                acc[nt] = __builtin_amdgcn_mfma_f32_32x32x16_bf16(Al, Bh, acc[nt], 0, 0, 0);
                acc[nt] = __builtin_amdgcn_mfma_f32_32x32x16_bf16(Ah, Bl, acc[nt], 0, 0, 0);
            }
        }
    }

    // epilogue: bias + relu + wave-local L2 norm + store fp32 z and bf16 zb
#pragma unroll
    for (int r = 0; r < 16; r++) {
        int mloc = (r & 3) + 8 * (r >> 2) + 4 * (lane >> 5);
        int grow = m0 + w * 32 + mloc;
        float v[8];
        float sumsq = 0.f;
#pragma unroll
        for (int nt = 0; nt < 8; nt++) {
            float t = acc[nt][r] + bb[nt];
            t = t > 0.f ? t : 0.f;
            v[nt] = t;
            sumsq += t * t;
        }
#pragma unroll
        for (int off = 16; off; off >>= 1) sumsq += __shfl_xor(sumsq, off, 64);
        float scale = 1.f / fmaxf(sqrtf(sumsq), 1e-12f);
        if (grow < N_NODES) {
            size_t rowb = (size_t)grow * OUT_DIM + (lane & 31);
#pragma unroll
            for (int nt = 0; nt < 8; nt++) {
                float zv = v[nt] * scale;
                z[rowb + nt * 32] = zv;
                if (zb) zb[rowb + nt * 32] = __builtin_bit_cast(ushort_t, (__bf16)zv);
            }
        }
    }
}

// ===========================================================================
// Fallback fp32 vector GEMM (used only if workspace too small)
// ===========================================================================
#define MBF 32
#define KTF 32
#define WPADF 36
__global__ __launch_bounds__(256, 3) void gemm_relu_norm(
    const float* __restrict__ h, const float* __restrict__ W,
    const float* __restrict__ b, float* __restrict__ z)
{
    __shared__ float hs[MBF][KTF];
    __shared__ float ws[OUT_DIM][WPADF];
    const int tid  = threadIdx.x;
    const int lane = tid & 63;
    const int wave = tid >> 6;
    const int r0   = wave * 8;
    const int m0   = blockIdx.x * MBF;
    float acc[8][4];
#pragma unroll
    for (int i = 0; i < 8; i++)
#pragma unroll
        for (int j = 0; j < 4; j++) acc[i][j] = 0.f;
    const int srow = tid >> 3;
    const int skj  = (tid & 7) * 4;
    for (int kt = 0; kt < IN_DIM; kt += KTF) {
        float4 hv = *(const float4*)&h[(size_t)(m0 + srow) * IN_DIM + kt + skj];
        float4 wv[8];
#pragma unroll
        for (int i = 0; i < 8; i++)
            wv[i] = *(const float4*)&W[(size_t)(srow + 32 * i) * IN_DIM + kt + skj];
        __syncthreads();
        *(float4*)&hs[srow][skj] = hv;
#pragma unroll
        for (int i = 0; i < 8; i++)
            *(float4*)&ws[srow + 32 * i][skj] = wv[i];
        __syncthreads();
#pragma unroll
        for (int kc = 0; kc < KTF / 4; kc++) {
            float4 wr[4];
#pragma unroll
            for (int j = 0; j < 4; j++)
                wr[j] = *(const float4*)&ws[lane + 64 * j][kc * 4];
            float4 hr[8];
#pragma unroll
            for (int i = 0; i < 8; i++)
                hr[i] = *(const float4*)&hs[r0 + i][kc * 4];
#pragma unroll
            for (int i = 0; i < 8; i++)
#pragma unroll
                for (int j = 0; j < 4; j++) {
                    acc[i][j] += hr[i].x * wr[j].x;
                    acc[i][j] += hr[i].y * wr[j].y;
                    acc[i][j] += hr[i].z * wr[j].z;
                    acc[i][j] += hr[i].w * wr[j].w;
                }
        }
    }
#pragma unroll
    for (int i = 0; i < 8; i++) {
        float v[4];
        float sumsq = 0.f;
#pragma unroll
        for (int j = 0; j < 4; j++) {
            float t = acc[i][j] + b[lane + 64 * j];
            t = t > 0.f ? t : 0.f;
            v[j] = t;
            sumsq += t * t;
        }
#pragma unroll
        for (int off = 32; off; off >>= 1) sumsq += __shfl_xor(sumsq, off, 64);
        float scale = 1.f / fmaxf(sqrtf(sumsq), 1e-12f);
        size_t row = (size_t)(m0 + r0 + i) * OUT_DIM;
#pragma unroll
        for (int j = 0; j < 4; j++)
            z[row + lane + 64 * j] = v[j] * scale;
    }
}

// ===========================================================================
// CSR build: degree histogram
// ===========================================================================
__global__ __launch_bounds__(256) void hist_kernel(
    const int* __restrict__ dst, unsigned* __restrict__ deg)
{
    int e = blockIdx.x * 256 + threadIdx.x;
    if (e < N_EDGES) atomicAdd(&deg[dst[e]], 1u);
}

// ===========================================================================
// 3-phase exclusive scan of deg -> offs (+ cursor copy)
// ===========================================================================
#define NCHUNK ((N_NODES + 255) / 256)   // 391

__global__ __launch_bounds__(256) void scan_local(
    const unsigned* __restrict__ deg, unsigned* __restrict__ offs,
    unsigned* __restrict__ bsum)
{
    __shared__ unsigned wt[4];
    int i = blockIdx.x * 256 + threadIdx.x;
    int lane = threadIdx.x & 63, w = threadIdx.x >> 6;
    unsigned v = (i < N_NODES) ? deg[i] : 0u;
    unsigned incl = v;
#pragma unroll
    for (int off = 1; off < 64; off <<= 1) {
        unsigned t = __shfl_up(incl, off, 64);
        if (lane >= off) incl += t;
    }
    if (lane == 63) wt[w] = incl;
    __syncthreads();
    unsigned wbase = 0;
    for (int j = 0; j < w; j++) wbase += wt[j];
    if (i < N_NODES) offs[i] = wbase + incl - v;
    if (threadIdx.x == 255) bsum[blockIdx.x] = wbase + incl;
}

__global__ __launch_bounds__(512) void scan_bsum(unsigned* __restrict__ bsum)
{
    __shared__ unsigned wt[8];
    int tid = threadIdx.x, lane = tid & 63, w = tid >> 6;
    unsigned v = (tid < NCHUNK) ? bsum[tid] : 0u;
    unsigned incl = v;
#pragma unroll
    for (int off = 1; off < 64; off <<= 1) {
        unsigned t = __shfl_up(incl, off, 64);
        if (lane >= off) incl += t;
    }
    if (lane == 63) wt[w] = incl;
    __syncthreads();
    unsigned wbase = 0;
    for (int j = 0; j < w; j++) wbase += wt[j];
    if (tid < NCHUNK) bsum[tid] = wbase + incl - v;   // exclusive
}

__global__ __launch_bounds__(256) void scan_add(
    unsigned* __restrict__ offs, const unsigned* __restrict__ bsum,
    unsigned* __restrict__ cursor)
{
    int i = blockIdx.x * 256 + threadIdx.x;
    if (i < N_NODES) {
        unsigned o = offs[i] + bsum[blockIdx.x];
        offs[i] = o;
        cursor[i] = o;
    }
}

// ===========================================================================
// Scatter src ids into dst-sorted order
// ===========================================================================
__global__ __launch_bounds__(256) void scatter_kernel(
    const int* __restrict__ src, const int* __restrict__ dst,
    unsigned* __restrict__ cursor, int* __restrict__ ssrc)
{
    int e = blockIdx.x * 256 + threadIdx.x;
    if (e < N_EDGES) {
        unsigned p = atomicAdd(&cursor[dst[e]], 1u);
        ssrc[p] = src[e];
    }
}

// ===========================================================================
// Gather-mean from bf16 mirror zb: one wave per node, 8 rows in flight.
// ===========================================================================
__global__ __launch_bounds__(256) void gather_mean_bf16(
    const ushort_t* __restrict__ zb, const int* __restrict__ ssrc,
    const unsigned* __restrict__ offs, const unsigned* __restrict__ deg,
    float* __restrict__ mean)
{
    int n = blockIdx.x * 4 + (threadIdx.x >> 6);
    if (n >= N_NODES) return;
    const int lane = threadIdx.x & 63;
    const unsigned start = offs[n];
    const unsigned dg = deg[n];

    float4 acc = {0.f, 0.f, 0.f, 0.f};
    for (unsigned base = 0; base < dg; base += 64) {
        int cnt = (int)min(64u, dg - base);
        int s_l = (lane < cnt) ? ssrc[start + base + lane] : 0;
        int j = 0;
        for (; j + 8 <= cnt; j += 8) {
            ushort4 u[8];
#pragma unroll
            for (int q = 0; q < 8; q++) {
                int s = __shfl(s_l, j + q, 64);
                u[q] = *(const ushort4*)&zb[(size_t)s * OUT_DIM + lane * 4];
            }
#pragma unroll
            for (int q = 0; q < 8; q++) {
                acc.x += bf2f(u[q].x);
                acc.y += bf2f(u[q].y);
                acc.z += bf2f(u[q].z);
                acc.w += bf2f(u[q].w);
            }
        }
        for (; j < cnt; j++) {
            int s = __shfl(s_l, j, 64);
            ushort4 u = *(const ushort4*)&zb[(size_t)s * OUT_DIM + lane * 4];
            acc.x += bf2f(u.x); acc.y += bf2f(u.y);
            acc.z += bf2f(u.z); acc.w += bf2f(u.w);
        }
    }
    float scale = dg > 0 ? 1.f / (float)dg : 0.f;
    float4 o = {acc.x * scale, acc.y * scale, acc.z * scale, acc.w * scale};
    *(float4*)&mean[(size_t)n * OUT_DIM + lane * 4] = o;
}

// fp32 gather (mid-tier fallback)
__global__ __launch_bounds__(256) void gather_mean(
    const float* __restrict__ z, const int* __restrict__ ssrc,
    const unsigned* __restrict__ offs, const unsigned* __restrict__ deg,
    float* __restrict__ mean)
{
    int n = blockIdx.x * 4 + (threadIdx.x >> 6);
    if (n >= N_NODES) return;
    const int lane = threadIdx.x & 63;
    const unsigned start = offs[n];
    const unsigned dg = deg[n];

    float4 acc = {0.f, 0.f, 0.f, 0.f};
    for (unsigned base = 0; base < dg; base += 64) {
        int cnt = (int)min(64u, dg - base);
        int s_l = (lane < cnt) ? ssrc[start + base + lane] : 0;
        int j = 0;
        for (; j + 4 <= cnt; j += 4) {
            int s0 = __shfl(s_l, j, 64);
            int s1 = __shfl(s_l, j + 1, 64);
            int s2 = __shfl(s_l, j + 2, 64);
            int s3 = __shfl(s_l, j + 3, 64);
            float4 v0 = *(const float4*)&z[(size_t)s0 * OUT_DIM + lane * 4];
            float4 v1 = *(const float4*)&z[(size_t)s1 * OUT_DIM + lane * 4];
            float4 v2 = *(const float4*)&z[(size_t)s2 * OUT_DIM + lane * 4];
            float4 v3 = *(const float4*)&z[(size_t)s3 * OUT_DIM + lane * 4];
            acc.x += v0.x + v1.x + v2.x + v3.x;
            acc.y += v0.y + v1.y + v2.y + v3.y;
            acc.z += v0.z + v1.z + v2.z + v3.z;
            acc.w += v0.w + v1.w + v2.w + v3.w;
        }
        for (; j < cnt; j++) {
            int s = __shfl(s_l, j, 64);
            float4 v = *(const float4*)&z[(size_t)s * OUT_DIM + lane * 4];
            acc.x += v.x; acc.y += v.y; acc.z += v.z; acc.w += v.w;
        }
    }
    float scale = dg > 0 ? 1.f / (float)dg : 0.f;
    float4 o = {acc.x * scale, acc.y * scale, acc.z * scale, acc.w * scale};
    *(float4*)&mean[(size_t)n * OUT_DIM + lane * 4] = o;
}

// ===========================================================================
// Legacy fallback: atomic aggregation
// ===========================================================================
__global__ __launch_bounds__(256) void agg_kernel(
    const float* __restrict__ z, const int* __restrict__ src,
    const int* __restrict__ dst, float* __restrict__ sums,
    unsigned int* __restrict__ deg)
{
    int e = blockIdx.x * 4 + (threadIdx.x >> 6);
    if (e >= N_EDGES) return;
    int lane = threadIdx.x & 63;
    int s = src[e];
    int d = dst[e];
    if (lane == 0) atomicAdd(&deg[d], 1u);
    float4 v = *(const float4*)&z[(size_t)s * OUT_DIM + lane * 4];
    float* o = &sums[(size_t)d * OUT_DIM + lane * 4];
    atomicAdd(o + 0, v.x);
    atomicAdd(o + 1, v.y);
    atomicAdd(o + 2, v.z);
    atomicAdd(o + 3, v.w);
}

__global__ __launch_bounds__(256) void finalize_kernel(
    float* __restrict__ sums, const unsigned int* __restrict__ deg)
{
    size_t i = (size_t)blockIdx.x * blockDim.x + threadIdx.x;
    if (i < (size_t)N_NODES * OUT_DIM) {
        unsigned int dg = deg[i >> 8];
        float s = sums[i];
        sums[i] = dg > 0 ? s / (float)dg : 0.f;
    }
}

extern "C" void kernel_launch(void* const* d_in, const int* in_sizes, int n_in,
                              void* d_out, int out_size, void* d_ws, size_t ws_size,
                              hipStream_t stream)
{
    const float* h   = (const float*)d_in[0];
    const float* W   = (const float*)d_in[1];
    const float* b   = (const float*)d_in[2];
    const int*   src = (const int*)d_in[3];
    const int*   dst = (const int*)d_in[4];

    float* z    = (float*)d_out;
    float* mean = z + (size_t)N_NODES * OUT_DIM;

    // ws layout (u32 words): Whi | Wlo | deg | offs | cursor | bsum | ssrc | zb
    const size_t WSPLIT = (size_t)OUT_DIM * IN_DIM / 2;   // 65536
    const size_t PAD = 100352;
    unsigned* whi_u  = (unsigned*)d_ws;
    unsigned* wlo_u  = whi_u + WSPLIT;
    unsigned* deg    = wlo_u + WSPLIT;
    unsigned* offs   = deg + PAD;
    unsigned* cursor = offs + PAD;
    unsigned* bsum   = cursor + PAD;
    int*      ssrc   = (int*)(bsum + 512);
    ushort_t* zbw    = (ushort_t*)(ssrc + N_EDGES);

    const size_t need_f32  = (WSPLIT * 2 + PAD * 3 + 512 + (size_t)N_EDGES) * 4;
    const size_t need_bf16 = need_f32 + (size_t)N_NODES * OUT_DIM * 2;

    if (ws_size >= need_f32) {
        bool use_bf16 = ws_size >= need_bf16;
        split_w<<<(OUT_DIM * IN_DIM) / 256, 256, 0, stream>>>(
            W, (ushort_t*)whi_u, (ushort_t*)wlo_u);
        gemm_mfma<<<(N_NODES + BM - 1) / BM, 256, 0, stream>>>(
            h, (const ushort_t*)whi_u, (const ushort_t*)wlo_u, b, z,
            use_bf16 ? zbw : (ushort_t*)nullptr);
        hipMemsetAsync(deg, 0, N_NODES * sizeof(unsigned), stream);
        hist_kernel<<<(N_EDGES + 255) / 256, 256, 0, stream>>>(dst, deg);
        scan_local<<<NCHUNK, 256, 0, stream>>>(deg, offs, bsum);
        scan_bsum<<<1, 512, 0, stream>>>(bsum);
        scan_add<<<NCHUNK, 256, 0, stream>>>(offs, bsum, cursor);
        scatter_kernel<<<(N_EDGES + 255) / 256, 256, 0, stream>>>(src, dst, cursor, ssrc);
        if (use_bf16)
            gather_mean_bf16<<<(N_NODES + 3) / 4, 256, 0, stream>>>(zbw, ssrc, offs, deg, mean);
        else
            gather_mean<<<(N_NODES + 3) / 4, 256, 0, stream>>>(z, ssrc, offs, deg, mean);
    } else {
        unsigned* deg2 = (unsigned*)d_ws;
        gemm_relu_norm<<<N_NODES / MBF, 256, 0, stream>>>(h, W, b, z);
        hipMemsetAsync(mean, 0, (size_t)N_NODES * OUT_DIM * sizeof(float), stream);
        hipMemsetAsync(deg2, 0, N_NODES * sizeof(unsigned), stream);
        agg_kernel<<<N_EDGES / 4, 256, 0, stream>>>(z, src, dst, mean, deg2);
        finalize_kernel<<<((size_t)N_NODES * OUT_DIM + 255) / 256, 256, 0, stream>>>(mean, deg2);
    }
}

// Round 9
// 927.933 us; speedup vs baseline: 12.6919x; 1.1403x over previous
//
#include <hip/hip_runtime.h>

#define N_NODES 100000
#define N_EDGES 3200000
#define IN_DIM 512
#define OUT_DIM 256

typedef unsigned short ushort_t;
typedef __bf16 bf16x8 __attribute__((ext_vector_type(8)));
typedef float f32x16 __attribute__((ext_vector_type(16)));

__device__ __forceinline__ float bf2f(ushort_t u) {
    return __uint_as_float((unsigned)u << 16);
}

// ===========================================================================
// W split: fp32 -> bf16 hi (truncate) + bf16 lo (RNE of remainder)
// ===========================================================================
__global__ __launch_bounds__(256) void split_w(
    const float* __restrict__ W, ushort_t* __restrict__ Whi, ushort_t* __restrict__ Wlo)
{
    int i = blockIdx.x * 256 + threadIdx.x;
    float x = W[i];
    unsigned xb = __float_as_uint(x);
    ushort_t h16 = (ushort_t)(xb >> 16);
    float hf = __uint_as_float((unsigned)h16 << 16);
    __bf16 lb = (__bf16)(x - hf);
    Whi[i] = h16;
    Wlo[i] = __builtin_bit_cast(ushort_t, lb);
}

// ===========================================================================
// MFMA GEMM: z = L2norm(relu(h @ W^T + b)), split-bf16 (3-term).
// Also writes zb = bf16(z) for the aggregation gather (if zb != nullptr).
// ===========================================================================
#define BM 128
#define BK 32

__device__ __forceinline__ int swz(int row, int col) {
    return row * 128 + (col ^ ((row & 7) << 4));
}

__global__ __launch_bounds__(256, 2) void gemm_mfma(
    const float* __restrict__ h, const ushort_t* __restrict__ Whi,
    const ushort_t* __restrict__ Wlo, const float* __restrict__ b,
    float* __restrict__ z, ushort_t* __restrict__ zb)
{
    __shared__ uint4 AsU[BM * 8];        // 16 KB
    __shared__ uint4 BsU[OUT_DIM * 8];   // 32 KB
    unsigned char* As = (unsigned char*)AsU;
    unsigned char* Bs = (unsigned char*)BsU;

    const int tid  = threadIdx.x;
    const int lane = tid & 63;
    const int w    = tid >> 6;
    const int m0   = blockIdx.x * BM;

    f32x16 acc[8];
#pragma unroll
    for (int i = 0; i < 8; i++)
#pragma unroll
        for (int e = 0; e < 16; e++) acc[i][e] = 0.f;

    float bb[8];
#pragma unroll
    for (int nt = 0; nt < 8; nt++) bb[nt] = b[nt * 32 + (lane & 31)];

    const int arow = tid >> 1;
    const int akh  = (tid & 1) * 16;

    for (int k0 = 0; k0 < IN_DIM; k0 += BK) {
        int grow = m0 + arow; if (grow > N_NODES - 1) grow = N_NODES - 1;
        const float* hp = &h[(size_t)grow * IN_DIM + k0 + akh];
        float4 v0 = *(const float4*)(hp);
        float4 v1 = *(const float4*)(hp + 4);
        float4 v2 = *(const float4*)(hp + 8);
        float4 v3 = *(const float4*)(hp + 12);
        const ushort_t* wh = &Whi[(size_t)tid * IN_DIM + k0];
        const ushort_t* wl = &Wlo[(size_t)tid * IN_DIM + k0];
        uint4 bh0 = *(const uint4*)(wh);
        uint4 bh1 = *(const uint4*)(wh + 8);
        uint4 bh2 = *(const uint4*)(wh + 16);
        uint4 bh3 = *(const uint4*)(wh + 24);
        uint4 bl0 = *(const uint4*)(wl);
        uint4 bl1 = *(const uint4*)(wl + 8);
        uint4 bl2 = *(const uint4*)(wl + 16);
        uint4 bl3 = *(const uint4*)(wl + 24);

        float f[16];
        f[0]=v0.x; f[1]=v0.y; f[2]=v0.z; f[3]=v0.w;
        f[4]=v1.x; f[5]=v1.y; f[6]=v1.z; f[7]=v1.w;
        f[8]=v2.x; f[9]=v2.y; f[10]=v2.z; f[11]=v2.w;
        f[12]=v3.x; f[13]=v3.y; f[14]=v3.z; f[15]=v3.w;
        unsigned hu[16], lu[16];
#pragma unroll
        for (int e = 0; e < 16; e++) {
            unsigned xb = __float_as_uint(f[e]);
            unsigned h16 = xb >> 16;
            float hf = __uint_as_float(h16 << 16);
            __bf16 lb = (__bf16)(f[e] - hf);
            hu[e] = h16;
            lu[e] = (unsigned)__builtin_bit_cast(ushort_t, lb);
        }
#define PK(a, i) ((a)[i] | ((a)[(i)+1] << 16))
        uint4 hc0 = { PK(hu,0), PK(hu,2), PK(hu,4),  PK(hu,6)  };
        uint4 hc1 = { PK(hu,8), PK(hu,10), PK(hu,12), PK(hu,14) };
        uint4 lc0 = { PK(lu,0), PK(lu,2), PK(lu,4),  PK(lu,6)  };
        uint4 lc1 = { PK(lu,8), PK(lu,10), PK(lu,12), PK(lu,14) };
#undef PK

        __syncthreads();

        *(uint4*)&As[swz(arow, 2 * akh)]       = hc0;
        *(uint4*)&As[swz(arow, 2 * akh + 16)]  = hc1;
        *(uint4*)&As[swz(arow, 64 + 2 * akh)]      = lc0;
        *(uint4*)&As[swz(arow, 64 + 2 * akh + 16)] = lc1;
        *(uint4*)&Bs[swz(tid, 0)]  = bh0;
        *(uint4*)&Bs[swz(tid, 16)] = bh1;
        *(uint4*)&Bs[swz(tid, 32)] = bh2;
        *(uint4*)&Bs[swz(tid, 48)] = bh3;
        *(uint4*)&Bs[swz(tid, 64)]  = bl0;
        *(uint4*)&Bs[swz(tid, 80)]  = bl1;
        *(uint4*)&Bs[swz(tid, 96)]  = bl2;
        *(uint4*)&Bs[swz(tid, 112)] = bl3;

        __syncthreads();

        const int mrow = w * 32 + (lane & 31);
        const int kb   = 16 * (lane >> 5);
#pragma unroll
        for (int s = 0; s < 2; s++) {
            bf16x8 Ah = __builtin_bit_cast(bf16x8, *(const uint4*)&As[swz(mrow, s * 32 + kb)]);
            bf16x8 Al = __builtin_bit_cast(bf16x8, *(const uint4*)&As[swz(mrow, 64 + s * 32 + kb)]);
#pragma unroll
            for (int nt = 0; nt < 8; nt++) {
                const int nrow = nt * 32 + (lane & 31);
                bf16x8 Bh = __builtin_bit_cast(bf16x8, *(const uint4*)&Bs[swz(nrow, s * 32 + kb)]);
                bf16x8 Bl = __builtin_bit_cast(bf16x8, *(const uint4*)&Bs[swz(nrow, 64 + s * 32 + kb)]);
                acc[nt] = __builtin_amdgcn_mfma_f32_32x32x16_bf16(Ah, Bh, acc[nt], 0, 0, 0);
                acc[nt] = __builtin_amdgcn_mfma_f32_32x32x16_bf16(Al, Bh, acc[nt], 0, 0, 0);
                acc[nt] = __builtin_amdgcn_mfma_f32_32x32x16_bf16(Ah, Bl, acc[nt], 0, 0, 0);
            }
        }
    }

    // epilogue: bias + relu + wave-local L2 norm + store fp32 z and bf16 zb
#pragma unroll
    for (int r = 0; r < 16; r++) {
        int mloc = (r & 3) + 8 * (r >> 2) + 4 * (lane >> 5);
        int grow = m0 + w * 32 + mloc;
        float v[8];
        float sumsq = 0.f;
#pragma unroll
        for (int nt = 0; nt < 8; nt++) {
            float t = acc[nt][r] + bb[nt];
            t = t > 0.f ? t : 0.f;
            v[nt] = t;
            sumsq += t * t;
        }
#pragma unroll
        for (int off = 16; off; off >>= 1) sumsq += __shfl_xor(sumsq, off, 64);
        float scale = 1.f / fmaxf(sqrtf(sumsq), 1e-12f);
        if (grow < N_NODES) {
            size_t rowb = (size_t)grow * OUT_DIM + (lane & 31);
#pragma unroll
            for (int nt = 0; nt < 8; nt++) {
                float zv = v[nt] * scale;
                z[rowb + nt * 32] = zv;
                if (zb) zb[rowb + nt * 32] = __builtin_bit_cast(ushort_t, (__bf16)zv);
            }
        }
    }
}

// ===========================================================================
// Fallback fp32 vector GEMM (used only if workspace too small)
// ===========================================================================
#define MBF 32
#define KTF 32
#define WPADF 36
__global__ __launch_bounds__(256, 3) void gemm_relu_norm(
    const float* __restrict__ h, const float* __restrict__ W,
    const float* __restrict__ b, float* __restrict__ z)
{
    __shared__ float hs[MBF][KTF];
    __shared__ float ws[OUT_DIM][WPADF];
    const int tid  = threadIdx.x;
    const int lane = tid & 63;
    const int wave = tid >> 6;
    const int r0   = wave * 8;
    const int m0   = blockIdx.x * MBF;
    float acc[8][4];
#pragma unroll
    for (int i = 0; i < 8; i++)
#pragma unroll
        for (int j = 0; j < 4; j++) acc[i][j] = 0.f;
    const int srow = tid >> 3;
    const int skj  = (tid & 7) * 4;
    for (int kt = 0; kt < IN_DIM; kt += KTF) {
        float4 hv = *(const float4*)&h[(size_t)(m0 + srow) * IN_DIM + kt + skj];
        float4 wv[8];
#pragma unroll
        for (int i = 0; i < 8; i++)
            wv[i] = *(const float4*)&W[(size_t)(srow + 32 * i) * IN_DIM + kt + skj];
        __syncthreads();
        *(float4*)&hs[srow][skj] = hv;
#pragma unroll
        for (int i = 0; i < 8; i++)
            *(float4*)&ws[srow + 32 * i][skj] = wv[i];
        __syncthreads();
#pragma unroll
        for (int kc = 0; kc < KTF / 4; kc++) {
            float4 wr[4];
#pragma unroll
            for (int j = 0; j < 4; j++)
                wr[j] = *(const float4*)&ws[lane + 64 * j][kc * 4];
            float4 hr[8];
#pragma unroll
            for (int i = 0; i < 8; i++)
                hr[i] = *(const float4*)&hs[r0 + i][kc * 4];
#pragma unroll
            for (int i = 0; i < 8; i++)
#pragma unroll
                for (int j = 0; j < 4; j++) {
                    acc[i][j] += hr[i].x * wr[j].x;
                    acc[i][j] += hr[i].y * wr[j].y;
                    acc[i][j] += hr[i].z * wr[j].z;
                    acc[i][j] += hr[i].w * wr[j].w;
                }
        }
    }
#pragma unroll
    for (int i = 0; i < 8; i++) {
        float v[4];
        float sumsq = 0.f;
#pragma unroll
        for (int j = 0; j < 4; j++) {
            float t = acc[i][j] + b[lane + 64 * j];
            t = t > 0.f ? t : 0.f;
            v[j] = t;
            sumsq += t * t;
        }
#pragma unroll
        for (int off = 32; off; off >>= 1) sumsq += __shfl_xor(sumsq, off, 64);
        float scale = 1.f / fmaxf(sqrtf(sumsq), 1e-12f);
        size_t row = (size_t)(m0 + r0 + i) * OUT_DIM;
#pragma unroll
        for (int j = 0; j < 4; j++)
            z[row + lane + 64 * j] = v[j] * scale;
    }
}

// ===========================================================================
// CSR build: degree histogram
// ===========================================================================
__global__ __launch_bounds__(256) void hist_kernel(
    const int* __restrict__ dst, unsigned* __restrict__ deg)
{
    int e = blockIdx.x * 256 + threadIdx.x;
    if (e < N_EDGES) atomicAdd(&deg[dst[e]], 1u);
}

// ===========================================================================
// 3-phase exclusive scan of deg -> offs (+ cursor copy)
// ===========================================================================
#define NCHUNK ((N_NODES + 255) / 256)   // 391

__global__ __launch_bounds__(256) void scan_local(
    const unsigned* __restrict__ deg, unsigned* __restrict__ offs,
    unsigned* __restrict__ bsum)
{
    __shared__ unsigned wt[4];
    int i = blockIdx.x * 256 + threadIdx.x;
    int lane = threadIdx.x & 63, w = threadIdx.x >> 6;
    unsigned v = (i < N_NODES) ? deg[i] : 0u;
    unsigned incl = v;
#pragma unroll
    for (int off = 1; off < 64; off <<= 1) {
        unsigned t = __shfl_up(incl, off, 64);
        if (lane >= off) incl += t;
    }
    if (lane == 63) wt[w] = incl;
    __syncthreads();
    unsigned wbase = 0;
    for (int j = 0; j < w; j++) wbase += wt[j];
    if (i < N_NODES) offs[i] = wbase + incl - v;
    if (threadIdx.x == 255) bsum[blockIdx.x] = wbase + incl;
}

__global__ __launch_bounds__(512) void scan_bsum(unsigned* __restrict__ bsum)
{
    __shared__ unsigned wt[8];
    int tid = threadIdx.x, lane = tid & 63, w = tid >> 6;
    unsigned v = (tid < NCHUNK) ? bsum[tid] : 0u;
    unsigned incl = v;
#pragma unroll
    for (int off = 1; off < 64; off <<= 1) {
        unsigned t = __shfl_up(incl, off, 64);
        if (lane >= off) incl += t;
    }
    if (lane == 63) wt[w] = incl;
    __syncthreads();
    unsigned wbase = 0;
    for (int j = 0; j < w; j++) wbase += wt[j];
    if (tid < NCHUNK) bsum[tid] = wbase + incl - v;   // exclusive
}

__global__ __launch_bounds__(256) void scan_add(
    unsigned* __restrict__ offs, const unsigned* __restrict__ bsum,
    unsigned* __restrict__ cursor)
{
    int i = blockIdx.x * 256 + threadIdx.x;
    if (i < N_NODES) {
        unsigned o = offs[i] + bsum[blockIdx.x];
        offs[i] = o;
        cursor[i] = o;
    }
}

// ===========================================================================
// Region-partitioned scatter: block b covers edge chunk (b>>3), region (b&7).
// Region = dst & 7 (100000 = 8*12500, perfectly balanced). With round-robin
// blockIdx->XCD, each output region is written by ONE XCD -> lines fill in
// that XCD's L2 before eviction -> kills the ~16x write amplification.
// ===========================================================================
#define SC_EC 8192
#define SC_NCH ((N_EDGES + SC_EC - 1) / SC_EC)   // 391

__global__ __launch_bounds__(256) void scatter_region(
    const int* __restrict__ src, const int* __restrict__ dst,
    unsigned* __restrict__ cursor, int* __restrict__ ssrc)
{
    const int r     = blockIdx.x & 7;
    const int chunk = blockIdx.x >> 3;
    const int e0 = chunk * SC_EC;
    const int e1 = min(e0 + SC_EC, N_EDGES);
    for (int e = e0 + threadIdx.x; e < e1; e += 256) {
        int d = dst[e];
        if ((d & 7) == r) {
            unsigned p = atomicAdd(&cursor[d], 1u);
            ssrc[p] = src[e];
        }
    }
}

// ===========================================================================
// Gather-mean from bf16 mirror zb: one wave per node, 8 rows in flight.
// ===========================================================================
__global__ __launch_bounds__(256) void gather_mean_bf16(
    const ushort_t* __restrict__ zb, const int* __restrict__ ssrc,
    const unsigned* __restrict__ offs, const unsigned* __restrict__ deg,
    float* __restrict__ mean)
{
    int n = blockIdx.x * 4 + (threadIdx.x >> 6);
    if (n >= N_NODES) return;
    const int lane = threadIdx.x & 63;
    const unsigned start = offs[n];
    const unsigned dg = deg[n];

    float4 acc = {0.f, 0.f, 0.f, 0.f};
    for (unsigned base = 0; base < dg; base += 64) {
        int cnt = (int)min(64u, dg - base);
        int s_l = (lane < cnt) ? ssrc[start + base + lane] : 0;
        int j = 0;
        for (; j + 8 <= cnt; j += 8) {
            ushort4 u[8];
#pragma unroll
            for (int q = 0; q < 8; q++) {
                int s = __shfl(s_l, j + q, 64);
                u[q] = *(const ushort4*)&zb[(size_t)s * OUT_DIM + lane * 4];
            }
#pragma unroll
            for (int q = 0; q < 8; q++) {
                acc.x += bf2f(u[q].x);
                acc.y += bf2f(u[q].y);
                acc.z += bf2f(u[q].z);
                acc.w += bf2f(u[q].w);
            }
        }
        for (; j < cnt; j++) {
            int s = __shfl(s_l, j, 64);
            ushort4 u = *(const ushort4*)&zb[(size_t)s * OUT_DIM + lane * 4];
            acc.x += bf2f(u.x); acc.y += bf2f(u.y);
            acc.z += bf2f(u.z); acc.w += bf2f(u.w);
        }
    }
    float scale = dg > 0 ? 1.f / (float)dg : 0.f;
    float4 o = {acc.x * scale, acc.y * scale, acc.z * scale, acc.w * scale};
    *(float4*)&mean[(size_t)n * OUT_DIM + lane * 4] = o;
}

// fp32 gather (mid-tier fallback)
__global__ __launch_bounds__(256) void gather_mean(
    const float* __restrict__ z, const int* __restrict__ ssrc,
    const unsigned* __restrict__ offs, const unsigned* __restrict__ deg,
    float* __restrict__ mean)
{
    int n = blockIdx.x * 4 + (threadIdx.x >> 6);
    if (n >= N_NODES) return;
    const int lane = threadIdx.x & 63;
    const unsigned start = offs[n];
    const unsigned dg = deg[n];

    float4 acc = {0.f, 0.f, 0.f, 0.f};
    for (unsigned base = 0; base < dg; base += 64) {
        int cnt = (int)min(64u, dg - base);
        int s_l = (lane < cnt) ? ssrc[start + base + lane] : 0;
        int j = 0;
        for (; j + 4 <= cnt; j += 4) {
            int s0 = __shfl(s_l, j, 64);
            int s1 = __shfl(s_l, j + 1, 64);
            int s2 = __shfl(s_l, j + 2, 64);
            int s3 = __shfl(s_l, j + 3, 64);
            float4 v0 = *(const float4*)&z[(size_t)s0 * OUT_DIM + lane * 4];
            float4 v1 = *(const float4*)&z[(size_t)s1 * OUT_DIM + lane * 4];
            float4 v2 = *(const float4*)&z[(size_t)s2 * OUT_DIM + lane * 4];
            float4 v3 = *(const float4*)&z[(size_t)s3 * OUT_DIM + lane * 4];
            acc.x += v0.x + v1.x + v2.x + v3.x;
            acc.y += v0.y + v1.y + v2.y + v3.y;
            acc.z += v0.z + v1.z + v2.z + v3.z;
            acc.w += v0.w + v1.w + v2.w + v3.w;
        }
        for (; j < cnt; j++) {
            int s = __shfl(s_l, j, 64);
            float4 v = *(const float4*)&z[(size_t)s * OUT_DIM + lane * 4];
            acc.x += v.x; acc.y += v.y; acc.z += v.z; acc.w += v.w;
        }
    }
    float scale = dg > 0 ? 1.f / (float)dg : 0.f;
    float4 o = {acc.x * scale, acc.y * scale, acc.z * scale, acc.w * scale};
    *(float4*)&mean[(size_t)n * OUT_DIM + lane * 4] = o;
}

// ===========================================================================
// Legacy fallback: atomic aggregation
// ===========================================================================
__global__ __launch_bounds__(256) void agg_kernel(
    const float* __restrict__ z, const int* __restrict__ src,
    const int* __restrict__ dst, float* __restrict__ sums,
    unsigned int* __restrict__ deg)
{
    int e = blockIdx.x * 4 + (threadIdx.x >> 6);
    if (e >= N_EDGES) return;
    int lane = threadIdx.x & 63;
    int s = src[e];
    int d = dst[e];
    if (lane == 0) atomicAdd(&deg[d], 1u);
    float4 v = *(const float4*)&z[(size_t)s * OUT_DIM + lane * 4];
    float* o = &sums[(size_t)d * OUT_DIM + lane * 4];
    atomicAdd(o + 0, v.x);
    atomicAdd(o + 1, v.y);
    atomicAdd(o + 2, v.z);
    atomicAdd(o + 3, v.w);
}

__global__ __launch_bounds__(256) void finalize_kernel(
    float* __restrict__ sums, const unsigned int* __restrict__ deg)
{
    size_t i = (size_t)blockIdx.x * blockDim.x + threadIdx.x;
    if (i < (size_t)N_NODES * OUT_DIM) {
        unsigned int dg = deg[i >> 8];
        float s = sums[i];
        sums[i] = dg > 0 ? s / (float)dg : 0.f;
    }
}

extern "C" void kernel_launch(void* const* d_in, const int* in_sizes, int n_in,
                              void* d_out, int out_size, void* d_ws, size_t ws_size,
                              hipStream_t stream)
{
    const float* h   = (const float*)d_in[0];
    const float* W   = (const float*)d_in[1];
    const float* b   = (const float*)d_in[2];
    const int*   src = (const int*)d_in[3];
    const int*   dst = (const int*)d_in[4];

    float* z    = (float*)d_out;
    float* mean = z + (size_t)N_NODES * OUT_DIM;

    // ws layout (u32 words): Whi | Wlo | deg | offs | cursor | bsum | ssrc | zb
    const size_t WSPLIT = (size_t)OUT_DIM * IN_DIM / 2;   // 65536
    const size_t PAD = 100352;
    unsigned* whi_u  = (unsigned*)d_ws;
    unsigned* wlo_u  = whi_u + WSPLIT;
    unsigned* deg    = wlo_u + WSPLIT;
    unsigned* offs   = deg + PAD;
    unsigned* cursor = offs + PAD;
    unsigned* bsum   = cursor + PAD;
    int*      ssrc   = (int*)(bsum + 512);
    ushort_t* zbw    = (ushort_t*)(ssrc + N_EDGES);

    const size_t need_f32  = (WSPLIT * 2 + PAD * 3 + 512 + (size_t)N_EDGES) * 4;
    const size_t need_bf16 = need_f32 + (size_t)N_NODES * OUT_DIM * 2;

    if (ws_size >= need_f32) {
        bool use_bf16 = ws_size >= need_bf16;
        split_w<<<(OUT_DIM * IN_DIM) / 256, 256, 0, stream>>>(
            W, (ushort_t*)whi_u, (ushort_t*)wlo_u);
        gemm_mfma<<<(N_NODES + BM - 1) / BM, 256, 0, stream>>>(
            h, (const ushort_t*)whi_u, (const ushort_t*)wlo_u, b, z,
            use_bf16 ? zbw : (ushort_t*)nullptr);
        hipMemsetAsync(deg, 0, N_NODES * sizeof(unsigned), stream);
        hist_kernel<<<(N_EDGES + 255) / 256, 256, 0, stream>>>(dst, deg);
        scan_local<<<NCHUNK, 256, 0, stream>>>(deg, offs, bsum);
        scan_bsum<<<1, 512, 0, stream>>>(bsum);
        scan_add<<<NCHUNK, 256, 0, stream>>>(offs, bsum, cursor);
        scatter_region<<<SC_NCH * 8, 256, 0, stream>>>(src, dst, cursor, ssrc);
        if (use_bf16)
            gather_mean_bf16<<<(N_NODES + 3) / 4, 256, 0, stream>>>(zbw, ssrc, offs, deg, mean);
        else
            gather_mean<<<(N_NODES + 3) / 4, 256, 0, stream>>>(z, ssrc, offs, deg, mean);
    } else {
        unsigned* deg2 = (unsigned*)d_ws;
        gemm_relu_norm<<<N_NODES / MBF, 256, 0, stream>>>(h, W, b, z);
        hipMemsetAsync(mean, 0, (size_t)N_NODES * OUT_DIM * sizeof(float), stream);
        hipMemsetAsync(deg2, 0, N_NODES * sizeof(unsigned), stream);
        agg_kernel<<<N_EDGES / 4, 256, 0, stream>>>(z, src, dst, mean, deg2);
        finalize_kernel<<<((size_t)N_NODES * OUT_DIM + 255) / 256, 256, 0, stream>>>(mean, deg2);
    }
}